// Round 18
// baseline (1730.447 us; speedup 1.0000x reference)
//
#include <hip/hip_runtime.h>

#define NT 1024
#define H0S 256
#define GS 64

typedef _Float16 half8 __attribute__((ext_vector_type(8)));
typedef _Float16 half4 __attribute__((ext_vector_type(4)));
typedef float f32x4 __attribute__((ext_vector_type(4)));
typedef unsigned long long u64;

#ifndef __has_builtin
#define __has_builtin(x) 0
#endif

__device__ __forceinline__ f32x4 MFMA(half8 a, half8 b, f32x4 c) {
  return __builtin_amdgcn_mfma_f32_16x16x32_f16(a, b, c, 0, 0, 0);
}
// Pade(7,6) rational tanh: 1 trans (rcp) + ~10 full-rate VALU.
// err <= 1.5e-5 for |x|<=4; ratio exceeds 1 monotonically beyond -> clamp.
__device__ __forceinline__ float tanhf2(float x) {
  float x2 = x * x;
  float n = fmaf(fmaf(x2 + 378.0f, x2, 17325.0f), x2, 135135.0f) * x;
  float d = fmaf(fmaf(fmaf(28.0f, x2, 3150.0f), x2, 62370.0f), x2, 135135.0f);
  float t = n * __builtin_amdgcn_rcpf(d);
  return fminf(fmaxf(t, -1.0f), 1.0f);
}
// sigmoid(x) = 0.5 + 0.5*tanh(x/2)
__device__ __forceinline__ float sigf(float x) {
  return fmaf(0.5f, tanhf2(0.5f * x), 0.5f);
}
__device__ __forceinline__ half8 cvt8(float4 c0, float4 c1) {
  half8 hv;
  hv[0] = (_Float16)c0.x; hv[1] = (_Float16)c0.y;
  hv[2] = (_Float16)c0.z; hv[3] = (_Float16)c0.w;
  hv[4] = (_Float16)c1.x; hv[5] = (_Float16)c1.y;
  hv[6] = (_Float16)c1.z; hv[7] = (_Float16)c1.w;
  return hv;
}
__device__ __forceinline__ unsigned wpoll(unsigned* p, unsigned tgt,
                                          unsigned cached, int l) {
  unsigned c = cached;
  while (c < tgt) {
    unsigned pv = 0;
    if (l == 0)
      pv = __hip_atomic_load(p, __ATOMIC_ACQUIRE, __HIP_MEMORY_SCOPE_AGENT);
    c = (unsigned)__builtin_amdgcn_readfirstlane((int)pv);
    if (c < tgt) __builtin_amdgcn_s_sleep(2);
  }
  return c;
}

#define DRAIN_BARRIER()                              \
  asm volatile("s_waitcnt vmcnt(0)" ::: "memory");   \
  __builtin_amdgcn_sched_barrier(0);                 \
  __builtin_amdgcn_s_barrier();                      \
  __builtin_amdgcn_sched_barrier(0)

#define LGKM_BARRIER()                               \
  asm volatile("s_waitcnt lgkmcnt(0)" ::: "memory"); \
  __builtin_amdgcn_sched_barrier(0);                 \
  __builtin_amdgcn_s_barrier();                      \
  __builtin_amdgcn_sched_barrier(0)

// Repack x [B,T,64] f32 -> f16 B-fragments Xf[g][t][kt][lane][8]
__global__ __launch_bounds__(256) void prep_x(const float* __restrict__ x,
                                              _Float16* __restrict__ Xf) {
  int t0 = blockIdx.x * 256 + threadIdx.x;
  int l = t0 & 63;
  int fid = t0 >> 6;                  // ((g*NT + t)*2 + kt)
  int kt = fid & 1;
  int t = (fid >> 1) & (NT - 1);
  int g = fid >> 11;
  int bt = g * 16 + (l & 15);
  int kb = kt * 32 + (l >> 4) * 4;
  const float* src = x + ((size_t)bt * NT + (size_t)t) * 64 + kb;
  float4 v0 = *(const float4*)src;
  float4 v1 = *(const float4*)(src + 16);
  *(half8*)(Xf + (size_t)fid * 512 + l * 8) = cvt8(v0, v1);
}

// 24 blocks x 512 threads. bid 0-7: P = self-sufficient layer-0 (24 MFMA +
// cell; h0 ring store, publish G=16). bid 8-15: X = gy1 producer (16 MFMA,
// consumes h0 ring off the critical path). bid 16-23: Y = layer-1 hh + FC +
// cell (20 MFMA, consumes gy ring 2-deep). Cell activations = rational
// tanh/sigmoid (1 rcp each) to lift the quarter-rate trans-pipe wall.
__global__ __launch_bounds__(512, 1) void lstm_main(
    const float* __restrict__ wih0, const float* __restrict__ whh0,
    const float* __restrict__ wih1, const float* __restrict__ whh1,
    const float* __restrict__ bih, const float* __restrict__ bhh,
    const float* __restrict__ fcw, const float* __restrict__ fcb,
    const _Float16* __restrict__ Xf, _Float16* __restrict__ h0R,
    float* __restrict__ gyR, unsigned* __restrict__ flags,
    float* __restrict__ out) {
  const int tid = threadIdx.x;
  const int w = tid >> 6, l = tid & 63;
  const int n = l & 15, lg = l >> 4;
  const int role = blockIdx.x >> 3;
  const int g = blockIdx.x & 7;

  __shared__ _Float16 hfr[2][4][64][8];   // own-layer h frags (8 KB)
  __shared__ _Float16 fcl[4][4][64][8];   // FC A-frags (Y only, 16 KB)

  _Float16* h0G = h0R + (size_t)g * H0S * 2048;
  float* gyG = gyR + (size_t)g * GS * 8192;
  unsigned* pP  = flags + (0 * 8 + g) * 16;   // P progress (release)
  unsigned* pXY = flags + (1 * 8 + g) * 16;   // X progress (release)
  unsigned* pY  = flags + (2 * 8 + g) * 16;   // Y progress (relaxed)
  const half8 hz = {0, 0, 0, 0, 0, 0, 0, 0};

  if (role == 0) {
    // ========= P: layer-0 self-sufficient (24 MFMA + cell) =========
    half8 A[4][6];
    f32x4 bias[4];
#pragma unroll
    for (int q = 0; q < 4; ++q) {
      int row = (w + 8 * q) * 16 + n;
#pragma unroll
      for (int kt = 0; kt < 2; ++kt) {
        const float* wp = wih0 + (size_t)row * 64 + kt * 32 + lg * 4;
        A[q][kt] = cvt8(*(const float4*)wp, *(const float4*)(wp + 16));
      }
#pragma unroll
      for (int kt = 0; kt < 4; ++kt) {
        const float* wp = whh0 + (size_t)row * 128 + kt * 32 + lg * 4;
        A[q][2 + kt] = cvt8(*(const float4*)wp, *(const float4*)(wp + 16));
      }
      int rb = (w + 8 * q) * 16 + lg * 4;
      f32x4 bv;
#pragma unroll
      for (int r = 0; r < 4; ++r) bv[r] = bih[rb + r] + bhh[rb + r];
      bias[q] = bv;
    }
    if (tid < 256) ((half8*)&hfr[1][0][0][0])[tid] = hz;  // h0[-1]=0
    const _Float16* XfG = Xf + (size_t)g * NT * 1024;
    half8 x0 = *(const half8*)(XfG + l * 8);
    half8 x1 = *(const half8*)(XfG + 512 + l * 8);
    f32x4 cst = {0.f, 0.f, 0.f, 0.f};
    unsigned XYp = 0;
    __syncthreads();
    for (int s = 0; s < NT; ++s) {
      half8 xn0, xn1;
      if (s + 1 < NT) {
        const _Float16* p = XfG + (size_t)(s + 1) * 1024 + l * 8;
        xn0 = *(const half8*)p;
        xn1 = *(const half8*)(p + 512);
      }
      if (s >= 224 && (s & 31) == 0)  // h0 ring backpressure vs X (cap 192)
        XYp = wpoll(pXY, (unsigned)(s - 192), XYp, l);
      const int rdk = (s + 1) & 1;
      half8 b2 = *(const half8*)&hfr[rdk][0][l][0];
      half8 b3 = *(const half8*)&hfr[rdk][1][l][0];
      half8 b4 = *(const half8*)&hfr[rdk][2][l][0];
      half8 b5 = *(const half8*)&hfr[rdk][3][l][0];
      f32x4 a0 = bias[0], a1 = bias[1], a2 = bias[2], a3 = bias[3];
      a0 = MFMA(A[0][0], x0, a0); a1 = MFMA(A[1][0], x0, a1);
      a2 = MFMA(A[2][0], x0, a2); a3 = MFMA(A[3][0], x0, a3);
      a0 = MFMA(A[0][1], x1, a0); a1 = MFMA(A[1][1], x1, a1);
      a2 = MFMA(A[2][1], x1, a2); a3 = MFMA(A[3][1], x1, a3);
      a0 = MFMA(A[0][2], b2, a0); a1 = MFMA(A[1][2], b2, a1);
      a2 = MFMA(A[2][2], b2, a2); a3 = MFMA(A[3][2], b2, a3);
      a0 = MFMA(A[0][3], b3, a0); a1 = MFMA(A[1][3], b3, a1);
      a2 = MFMA(A[2][3], b3, a2); a3 = MFMA(A[3][3], b3, a3);
      a0 = MFMA(A[0][4], b4, a0); a1 = MFMA(A[1][4], b4, a1);
      a2 = MFMA(A[2][4], b4, a2); a3 = MFMA(A[3][4], b4, a3);
      a0 = MFMA(A[0][5], b5, a0); a1 = MFMA(A[1][5], b5, a1);
      a2 = MFMA(A[2][5], b5, a2); a3 = MFMA(A[3][5], b5, a3);
      half4 hh;
#pragma unroll
      for (int r = 0; r < 4; ++r) {
        float iv = sigf(a0[r]), fv = sigf(a1[r]);
        float gv = tanhf2(a2[r]), ov = sigf(a3[r]);
        cst[r] = fv * cst[r] + iv * gv;
        hh[r] = (_Float16)(ov * tanhf2(cst[r]));
      }
      *(half4*)&hfr[s & 1][w >> 1][l][(w & 1) << 2] = hh;
      *(u64*)(h0G + (size_t)(s & (H0S - 1)) * 2048 + (w >> 1) * 512 + l * 8 +
              (w & 1) * 4) = __builtin_bit_cast(u64, hh);
      LGKM_BARRIER();  // ring store + x prefetch stay in flight
      if ((s & 15) == 15) {
        DRAIN_BARRIER();
        if (tid == 0)
          __hip_atomic_store(pP, (unsigned)(s + 1), __ATOMIC_RELEASE,
                             __HIP_MEMORY_SCOPE_AGENT);
      }
      x0 = xn0;
      x1 = xn1;
    }
  } else if (role == 1) {
    // ========= X: gy1[u] = b1 + Wih1 h0[u]  (16 MFMA, off-path) =========
    half8 Ai[4][4];
    f32x4 b1v[4];
#pragma unroll
    for (int q = 0; q < 4; ++q) {
      int row = (w + 8 * q) * 16 + n;
#pragma unroll
      for (int kt = 0; kt < 4; ++kt) {
        const float* wp = wih1 + (size_t)row * 128 + kt * 32 + lg * 4;
        Ai[q][kt] = cvt8(*(const float4*)wp, *(const float4*)(wp + 16));
      }
      int rb = (w + 8 * q) * 16 + lg * 4;
      f32x4 bv;
#pragma unroll
      for (int r = 0; r < 4; ++r)
        bv[r] = bih[512 + rb + r] + bhh[512 + rb + r];
      b1v[q] = bv;
    }
    unsigned Pp = wpoll(pP, 2u, 0u, l), Yp = 0;
    const _Float16* hp0 = h0G + l * 8;
    half8 hA0 = *(const half8*)hp0;
    half8 hA1 = *(const half8*)(hp0 + 512);
    half8 hA2 = *(const half8*)(hp0 + 1024);
    half8 hA3 = *(const half8*)(hp0 + 1536);
    const _Float16* hp1 = h0G + 2048 + l * 8;
    half8 hB0 = *(const half8*)hp1;
    half8 hB1 = *(const half8*)(hp1 + 512);
    half8 hB2 = *(const half8*)(hp1 + 1024);
    half8 hB3 = *(const half8*)(hp1 + 1536);

#define XSTEP(U, H0_, H1_, H2_, H3_)                                           \
  {                                                                            \
    f32x4 c0 = b1v[0], c1 = b1v[1], c2 = b1v[2], c3 = b1v[3];                  \
    c0 = MFMA(Ai[0][0], H0_, c0); c1 = MFMA(Ai[1][0], H0_, c1);                \
    c2 = MFMA(Ai[2][0], H0_, c2); c3 = MFMA(Ai[3][0], H0_, c3);                \
    c0 = MFMA(Ai[0][1], H1_, c0); c1 = MFMA(Ai[1][1], H1_, c1);                \
    c2 = MFMA(Ai[2][1], H1_, c2); c3 = MFMA(Ai[3][1], H1_, c3);                \
    c0 = MFMA(Ai[0][2], H2_, c0); c1 = MFMA(Ai[1][2], H2_, c1);                \
    c2 = MFMA(Ai[2][2], H2_, c2); c3 = MFMA(Ai[3][2], H2_, c3);                \
    c0 = MFMA(Ai[0][3], H3_, c0); c1 = MFMA(Ai[1][3], H3_, c1);                \
    c2 = MFMA(Ai[2][3], H3_, c2); c3 = MFMA(Ai[3][3], H3_, c3);                \
    float* gp = gyG + (size_t)((U) & (GS - 1)) * 8192;                         \
    *(f32x4*)(gp + ((0 + w) * 64 + l) * 4) = c0;                               \
    *(f32x4*)(gp + ((8 + w) * 64 + l) * 4) = c1;                               \
    *(f32x4*)(gp + ((16 + w) * 64 + l) * 4) = c2;                              \
    *(f32x4*)(gp + ((24 + w) * 64 + l) * 4) = c3;                              \
    if ((U) + 2 < NT) { /* reload this slot pair with h0[U+2] */               \
      Pp = wpoll(pP, (unsigned)((U) + 3), Pp, l);                              \
      const _Float16* hp_ =                                                    \
          h0G + (size_t)(((U) + 2) & (H0S - 1)) * 2048 + l * 8;                \
      H0_ = *(const half8*)hp_;                                                \
      H1_ = *(const half8*)(hp_ + 512);                                        \
      H2_ = *(const half8*)(hp_ + 1024);                                       \
      H3_ = *(const half8*)(hp_ + 1536);                                       \
    }                                                                          \
    if (((U) & 15) == 0 && (U) >= 48) /* gy ring backpressure (cap 40) */      \
      Yp = wpoll(pY, (unsigned)((U) - 40), Yp, l);                             \
    if (((U) & 15) == 15) {                                                    \
      DRAIN_BARRIER();                                                         \
      if (tid == 0)                                                            \
        __hip_atomic_store(pXY, (unsigned)((U) + 1), __ATOMIC_RELEASE,         \
                           __HIP_MEMORY_SCOPE_AGENT);                          \
    }                                                                          \
  }

    for (int u = 0; u < NT; u += 2) {
      XSTEP(u, hA0, hA1, hA2, hA3);
      XSTEP(u + 1, hB0, hB1, hB2, hB3);
    }
#undef XSTEP
  } else {
    // ======= Y: layer-1 hh (16) + FC (4) + cell, consumes gy ring =======
    half8 Ah[4][4];
    f32x4 fcbv = {0.f, 0.f, 0.f, 0.f};
#pragma unroll
    for (int q = 0; q < 4; ++q) {
      int row = (w + 8 * q) * 16 + n;
#pragma unroll
      for (int kt = 0; kt < 4; ++kt) {
        const float* wp = whh1 + (size_t)row * 128 + kt * 32 + lg * 4;
        Ah[q][kt] = cvt8(*(const float4*)wp, *(const float4*)(wp + 16));
      }
    }
    if (w < 4) {  // FC A-frags -> LDS
      int frow = (w << 4) + n;
#pragma unroll
      for (int kt = 0; kt < 4; ++kt) {
        const float* wp = fcw + (size_t)frow * 128 + kt * 32 + lg * 4;
        *(half8*)&fcl[w][kt][l][0] =
            cvt8(*(const float4*)wp, *(const float4*)(wp + 16));
      }
      fcbv = *(const f32x4*)(fcb + (w << 4) + lg * 4);
    }
    if (tid < 256) ((half8*)&hfr[1][0][0][0])[tid] = hz;  // h1[-1]=0
    float* outG = out + (size_t)((g << 4) + n) * NT * 64 + (w << 4) + lg * 4;
    f32x4 cst = {0.f, 0.f, 0.f, 0.f};
    __syncthreads();
    unsigned XYp = wpoll(pXY, 2u, 0u, l);
    f32x4 gA0 = *(const f32x4*)(gyG + ((0 + w) * 64 + l) * 4);
    f32x4 gA1 = *(const f32x4*)(gyG + ((8 + w) * 64 + l) * 4);
    f32x4 gA2 = *(const f32x4*)(gyG + ((16 + w) * 64 + l) * 4);
    f32x4 gA3 = *(const f32x4*)(gyG + ((24 + w) * 64 + l) * 4);
    const float* g1p = gyG + 8192;
    f32x4 gB0 = *(const f32x4*)(g1p + ((0 + w) * 64 + l) * 4);
    f32x4 gB1 = *(const f32x4*)(g1p + ((8 + w) * 64 + l) * 4);
    f32x4 gB2 = *(const f32x4*)(g1p + ((16 + w) * 64 + l) * 4);
    f32x4 gB3 = *(const f32x4*)(g1p + ((24 + w) * 64 + l) * 4);

#define YSTEP(T, G0, G1, G2, G3)                                               \
  {                                                                            \
    const int rdk_ = ((T) + 1) & 1;                                            \
    half8 b0 = *(const half8*)&hfr[rdk_][0][l][0];                             \
    half8 b1 = *(const half8*)&hfr[rdk_][1][l][0];                             \
    half8 b2 = *(const half8*)&hfr[rdk_][2][l][0];                             \
    half8 b3 = *(const half8*)&hfr[rdk_][3][l][0];                             \
    f32x4 c0 = G0, c1 = G1, c2 = G2, c3 = G3;                                  \
    c0 = MFMA(Ah[0][0], b0, c0); c1 = MFMA(Ah[1][0], b0, c1);                  \
    c2 = MFMA(Ah[2][0], b0, c2); c3 = MFMA(Ah[3][0], b0, c3);                  \
    c0 = MFMA(Ah[0][1], b1, c0); c1 = MFMA(Ah[1][1], b1, c1);                  \
    c2 = MFMA(Ah[2][1], b1, c2); c3 = MFMA(Ah[3][1], b1, c3);                  \
    c0 = MFMA(Ah[0][2], b2, c0); c1 = MFMA(Ah[1][2], b2, c1);                  \
    c2 = MFMA(Ah[2][2], b2, c2); c3 = MFMA(Ah[3][2], b2, c3);                  \
    c0 = MFMA(Ah[0][3], b3, c0); c1 = MFMA(Ah[1][3], b3, c1);                  \
    c2 = MFMA(Ah[2][3], b3, c2); c3 = MFMA(Ah[3][3], b3, c3);                  \
    if (w < 4) { /* FC of h1[T-1] */                                           \
      half8 f0 = *(const half8*)&fcl[w][0][l][0];                              \
      half8 f1 = *(const half8*)&fcl[w][1][l][0];                              \
      half8 f2 = *(const half8*)&fcl[w][2][l][0];                              \
      half8 f3 = *(const half8*)&fcl[w][3][l][0];                              \
      f32x4 afc = fcbv;                                                        \
      afc = MFMA(f0, b0, afc); afc = MFMA(f1, b1, afc);                        \
      afc = MFMA(f2, b2, afc); afc = MFMA(f3, b3, afc);                        \
      if ((T) >= 1) *(f32x4*)(outG + (size_t)((T) - 1) * 64) = afc;            \
    }                                                                          \
    if ((T) + 2 < NT) { /* prefetch gy[T+2] */                                 \
      XYp = wpoll(pXY, (unsigned)((T) + 3), XYp, l);                           \
      const float* gp_ = gyG + (size_t)(((T) + 2) & (GS - 1)) * 8192;          \
      G0 = *(const f32x4*)(gp_ + ((0 + w) * 64 + l) * 4);                      \
      G1 = *(const f32x4*)(gp_ + ((8 + w) * 64 + l) * 4);                      \
      G2 = *(const f32x4*)(gp_ + ((16 + w) * 64 + l) * 4);                     \
      G3 = *(const f32x4*)(gp_ + ((24 + w) * 64 + l) * 4);                     \
    }                                                                          \
    half4 hh;                                                                  \
    _Pragma("unroll")                                                          \
    for (int r = 0; r < 4; ++r) {                                              \
      float iv = sigf(c0[r]), fv = sigf(c1[r]);                                \
      float gv = tanhf2(c2[r]), ov = sigf(c3[r]);                              \
      cst[r] = fv * cst[r] + iv * gv;                                          \
      hh[r] = (_Float16)(ov * tanhf2(cst[r]));                                 \
    }                                                                          \
    *(half4*)&hfr[(T) & 1][w >> 1][l][(w & 1) << 2] = hh;                      \
    LGKM_BARRIER();                                                            \
    if (((T) & 15) == 15 && tid == 0)                                          \
      __hip_atomic_store(pY, (unsigned)((T) + 1), __ATOMIC_RELAXED,            \
                         __HIP_MEMORY_SCOPE_AGENT);                            \
  }

    for (int t = 0; t < NT; t += 2) {
      YSTEP(t, gA0, gA1, gA2, gA3);
      YSTEP(t + 1, gB0, gB1, gB2, gB3);
    }
#undef YSTEP
    {  // epilogue: FC of h1[NT-1] -> out[NT-1]
      const int rdk = (NT + 1) & 1;
      half8 b0 = *(const half8*)&hfr[rdk][0][l][0];
      half8 b1 = *(const half8*)&hfr[rdk][1][l][0];
      half8 b2 = *(const half8*)&hfr[rdk][2][l][0];
      half8 b3 = *(const half8*)&hfr[rdk][3][l][0];
      if (w < 4) {
        half8 f0 = *(const half8*)&fcl[w][0][l][0];
        half8 f1 = *(const half8*)&fcl[w][1][l][0];
        half8 f2 = *(const half8*)&fcl[w][2][l][0];
        half8 f3 = *(const half8*)&fcl[w][3][l][0];
        f32x4 afc = fcbv;
        afc = MFMA(f0, b0, afc); afc = MFMA(f1, b1, afc);
        afc = MFMA(f2, b2, afc); afc = MFMA(f3, b3, afc);
        *(f32x4*)(outG + (size_t)(NT - 1) * 64) = afc;
      }
    }
  }
}

extern "C" void kernel_launch(void* const* d_in, const int* in_sizes, int n_in,
                              void* d_out, int out_size, void* d_ws, size_t ws_size,
                              hipStream_t stream) {
  const float* x     = (const float*)d_in[0];
  const float* w_ih0 = (const float*)d_in[1];
  const float* w_hh0 = (const float*)d_in[2];
  const float* w_ih1 = (const float*)d_in[3];
  const float* w_hh1 = (const float*)d_in[4];
  const float* b_ih  = (const float*)d_in[5];
  const float* b_hh  = (const float*)d_in[6];
  const float* fc_w  = (const float*)d_in[7];
  const float* fc_b  = (const float*)d_in[8];

  // ws: Xf 16MB | h0R 8MB | gyR 16MB | flags 4KB  (= 40MB+4KB)
  _Float16* Xf  = (_Float16*)d_ws;
  _Float16* h0R = (_Float16*)((char*)d_ws + (16u << 20));
  float* gyR    = (float*)((char*)d_ws + (24u << 20));
  unsigned* flags = (unsigned*)((char*)d_ws + (40u << 20));

  (void)hipMemsetAsync(flags, 0, 4096, stream);
  prep_x<<<4096, 256, 0, stream>>>(x, Xf);
  lstm_main<<<24, 512, 0, stream>>>(w_ih0, w_hh0, w_ih1, w_hh1, b_ih, b_hh,
                                    fc_w, fc_b, Xf, h0R, gyR, flags,
                                    (float*)d_out);
}

// Round 19
// 1227.983 us; speedup vs baseline: 1.4092x; 1.4092x over previous
//
#include <hip/hip_runtime.h>

#define NT 1024
#define H0S 256
#define GS 64
#define LAG 32

typedef _Float16 half8 __attribute__((ext_vector_type(8)));
typedef _Float16 half4 __attribute__((ext_vector_type(4)));
typedef float f32x4 __attribute__((ext_vector_type(4)));
typedef unsigned long long u64;

#ifndef __has_builtin
#define __has_builtin(x) 0
#endif

__device__ __forceinline__ f32x4 MFMA(half8 a, half8 b, f32x4 c) {
  return __builtin_amdgcn_mfma_f32_16x16x32_f16(a, b, c, 0, 0, 0);
}
__device__ __forceinline__ float exp2h(float x) {
#if __has_builtin(__builtin_amdgcn_exp2f)
  return __builtin_amdgcn_exp2f(x);
#else
  return exp2f(x);
#endif
}
__device__ __forceinline__ float sigf(float x) {
  return __builtin_amdgcn_rcpf(1.0f + exp2h(x * -1.44269504f));
}
__device__ __forceinline__ float tanhf2(float x) {
  float t = __builtin_amdgcn_rcpf(1.0f + exp2h(x * 2.88539008f));
  return fmaf(-2.0f, t, 1.0f);
}
__device__ __forceinline__ half8 cvt8(float4 c0, float4 c1) {
  half8 hv;
  hv[0] = (_Float16)c0.x; hv[1] = (_Float16)c0.y;
  hv[2] = (_Float16)c0.z; hv[3] = (_Float16)c0.w;
  hv[4] = (_Float16)c1.x; hv[5] = (_Float16)c1.y;
  hv[6] = (_Float16)c1.z; hv[7] = (_Float16)c1.w;
  return hv;
}
__device__ __forceinline__ unsigned wpoll(unsigned* p, unsigned tgt,
                                          unsigned cached, int l) {
  unsigned c = cached;
  while (c < tgt) {
    unsigned pv = 0;
    if (l == 0)
      pv = __hip_atomic_load(p, __ATOMIC_ACQUIRE, __HIP_MEMORY_SCOPE_AGENT);
    c = (unsigned)__builtin_amdgcn_readfirstlane((int)pv);
    if (c < tgt) __builtin_amdgcn_s_sleep(2);
  }
  return c;
}

#define DRAIN_BARRIER()                              \
  asm volatile("s_waitcnt vmcnt(0)" ::: "memory");   \
  __builtin_amdgcn_sched_barrier(0);                 \
  __builtin_amdgcn_s_barrier();                      \
  __builtin_amdgcn_sched_barrier(0)

#define LGKM_BARRIER()                               \
  asm volatile("s_waitcnt lgkmcnt(0)" ::: "memory"); \
  __builtin_amdgcn_sched_barrier(0);                 \
  __builtin_amdgcn_s_barrier();                      \
  __builtin_amdgcn_sched_barrier(0)

// Repack x [B,T,64] f32 -> f16 B-fragments Xf[g][t][kt][lane][8]
__global__ __launch_bounds__(256) void prep_x(const float* __restrict__ x,
                                              _Float16* __restrict__ Xf) {
  int t0 = blockIdx.x * 256 + threadIdx.x;
  int l = t0 & 63;
  int fid = t0 >> 6;                  // ((g*NT + t)*2 + kt)
  int kt = fid & 1;
  int t = (fid >> 1) & (NT - 1);
  int g = fid >> 11;
  int bt = g * 16 + (l & 15);
  int kb = kt * 32 + (l >> 4) * 4;
  const float* src = x + ((size_t)bt * NT + (size_t)t) * 64 + kb;
  float4 v0 = *(const float4*)src;
  float4 v1 = *(const float4*)(src + 16);
  *(half8*)(Xf + (size_t)fid * 512 + l * 8) = cvt8(v0, v1);
}

// 24 blocks x 512 threads. role = bid>>3: 0 = X (input-side GEMMs gx0,gy1),
// 1 = P (layer-0 recurrence, hh only), 2 = Y (layer-1 recurrence + FC).
// LAG=32 (deadlock bound 17 at publish-granularity 8; feasibility band for
// the X<->P loop is 10..23 steps — widest of the tested cadences).
// Ring DATA = plain coalesced vector ops; cross-CU visibility via drained
// release flags + acquire polls (R6-proven). Best measured: 1231 us.
__global__ __launch_bounds__(512, 1) void lstm_main(
    const float* __restrict__ wih0, const float* __restrict__ whh0,
    const float* __restrict__ wih1, const float* __restrict__ whh1,
    const float* __restrict__ bih, const float* __restrict__ bhh,
    const float* __restrict__ fcw, const float* __restrict__ fcb,
    const _Float16* __restrict__ Xf, _Float16* __restrict__ h0R,
    float* __restrict__ gxR, float* __restrict__ gyR,
    unsigned* __restrict__ flags, float* __restrict__ out) {
  const int tid = threadIdx.x;
  const int w = tid >> 6, l = tid & 63;
  const int n = l & 15, lg = l >> 4;
  const int role = blockIdx.x >> 3;
  const int g = blockIdx.x & 7;

  __shared__ _Float16 hfr[2][4][64][8];

  _Float16* h0G = h0R + (size_t)g * H0S * 2048;
  float* gxG = gxR + (size_t)g * GS * 8192;
  float* gyG = gyR + (size_t)g * GS * 8192;
  unsigned* pX  = flags + (0 * 8 + g) * 16;
  unsigned* pXY = flags + (1 * 8 + g) * 16;
  unsigned* pP  = flags + (2 * 8 + g) * 16;
  unsigned* pY  = flags + (3 * 8 + g) * 16;
  const half8 hz = {0, 0, 0, 0, 0, 0, 0, 0};

  if (role == 0) {
    // ================= X: gx0[s] & gy1[u=s-LAG] GEMMs =================
    half8 Ax[4][2], Ai[4][4];
    f32x4 b0v[4], b1v[4];
#pragma unroll
    for (int q = 0; q < 4; ++q) {
      int row = (w + 8 * q) * 16 + n;
#pragma unroll
      for (int kt = 0; kt < 2; ++kt) {
        const float* wp = wih0 + (size_t)row * 64 + kt * 32 + lg * 4;
        Ax[q][kt] = cvt8(*(const float4*)wp, *(const float4*)(wp + 16));
      }
#pragma unroll
      for (int kt = 0; kt < 4; ++kt) {
        const float* wp = wih1 + (size_t)row * 128 + kt * 32 + lg * 4;
        Ai[q][kt] = cvt8(*(const float4*)wp, *(const float4*)(wp + 16));
      }
      int rb = (w + 8 * q) * 16 + lg * 4;
      f32x4 v0, v1;
#pragma unroll
      for (int r = 0; r < 4; ++r) {
        v0[r] = bih[rb + r] + bhh[rb + r];
        v1[r] = bih[512 + rb + r] + bhh[512 + rb + r];
      }
      b0v[q] = v0;
      b1v[q] = v1;
    }
    const _Float16* XfG = Xf + (size_t)g * NT * 1024;
    half8 xv0 = *(const half8*)(XfG + l * 8);
    half8 xv1 = *(const half8*)(XfG + 512 + l * 8);
    half8 hb0 = hz, hb1 = hz, hb2 = hz, hb3 = hz;
    unsigned Pp = 0, Yp = 0;
    for (int s = 0; s < NT + LAG; ++s) {
      const int u = s - LAG;
      if (s < NT) {  // gx0[s]
        f32x4 a0 = MFMA(Ax[0][0], xv0, b0v[0]);
        f32x4 a1 = MFMA(Ax[1][0], xv0, b0v[1]);
        f32x4 a2 = MFMA(Ax[2][0], xv0, b0v[2]);
        f32x4 a3 = MFMA(Ax[3][0], xv0, b0v[3]);
        a0 = MFMA(Ax[0][1], xv1, a0); a1 = MFMA(Ax[1][1], xv1, a1);
        a2 = MFMA(Ax[2][1], xv1, a2); a3 = MFMA(Ax[3][1], xv1, a3);
        float* gp = gxG + (size_t)(s & (GS - 1)) * 8192;
        *(f32x4*)(gp + ((0 + w) * 64 + l) * 4) = a0;
        *(f32x4*)(gp + ((8 + w) * 64 + l) * 4) = a1;
        *(f32x4*)(gp + ((16 + w) * 64 + l) * 4) = a2;
        *(f32x4*)(gp + ((24 + w) * 64 + l) * 4) = a3;
        if (s + 1 < NT) {
          const _Float16* p = XfG + (size_t)(s + 1) * 1024 + l * 8;
          xv0 = *(const half8*)p;
          xv1 = *(const half8*)(p + 512);
        }
      }
      if (u >= 0) {  // gy1[u] = b1 + Wih1 h0[u]
        if (u == 0) {  // cold load h0[0]
          Pp = wpoll(pP, 1u, Pp, l);
          const _Float16* hp = h0G + l * 8;
          hb0 = *(const half8*)hp;
          hb1 = *(const half8*)(hp + 512);
          hb2 = *(const half8*)(hp + 1024);
          hb3 = *(const half8*)(hp + 1536);
        }
        f32x4 c0 = MFMA(Ai[0][0], hb0, b1v[0]);
        f32x4 c1 = MFMA(Ai[1][0], hb0, b1v[1]);
        f32x4 c2 = MFMA(Ai[2][0], hb0, b1v[2]);
        f32x4 c3 = MFMA(Ai[3][0], hb0, b1v[3]);
        c0 = MFMA(Ai[0][1], hb1, c0); c1 = MFMA(Ai[1][1], hb1, c1);
        c2 = MFMA(Ai[2][1], hb1, c2); c3 = MFMA(Ai[3][1], hb1, c3);
        c0 = MFMA(Ai[0][2], hb2, c0); c1 = MFMA(Ai[1][2], hb2, c1);
        c2 = MFMA(Ai[2][2], hb2, c2); c3 = MFMA(Ai[3][2], hb2, c3);
        c0 = MFMA(Ai[0][3], hb3, c0); c1 = MFMA(Ai[1][3], hb3, c1);
        c2 = MFMA(Ai[2][3], hb3, c2); c3 = MFMA(Ai[3][3], hb3, c3);
        float* gp = gyG + (size_t)(u & (GS - 1)) * 8192;
        *(f32x4*)(gp + ((0 + w) * 64 + l) * 4) = c0;
        *(f32x4*)(gp + ((8 + w) * 64 + l) * 4) = c1;
        *(f32x4*)(gp + ((16 + w) * 64 + l) * 4) = c2;
        *(f32x4*)(gp + ((24 + w) * 64 + l) * 4) = c3;
        if (u + 1 < NT) {  // prefetch h0[u+1]
          Pp = wpoll(pP, (unsigned)(u + 2), Pp, l);
          const _Float16* hp =
              h0G + (size_t)((u + 1) & (H0S - 1)) * 2048 + l * 8;
          hb0 = *(const half8*)hp;
          hb1 = *(const half8*)(hp + 512);
          hb2 = *(const half8*)(hp + 1024);
          hb3 = *(const half8*)(hp + 1536);
        }
        if ((u & 15) == 0 && u >= 56)  // gy ring backpressure vs Y
          Yp = wpoll(pY, (unsigned)(u - 48), Yp, l);
      }
      if ((s & 7) == 7) {  // drained release publish (both rings)
        DRAIN_BARRIER();
        if (tid == 0) {
          __hip_atomic_store(pX, (unsigned)(s + 1), __ATOMIC_RELEASE,
                             __HIP_MEMORY_SCOPE_AGENT);
          if (u >= 0)
            __hip_atomic_store(pXY, (unsigned)(u + 1), __ATOMIC_RELEASE,
                               __HIP_MEMORY_SCOPE_AGENT);
        }
      }
    }
    DRAIN_BARRIER();
    if (tid == 0) {
      __hip_atomic_store(pX, (unsigned)(NT + LAG), __ATOMIC_RELEASE,
                         __HIP_MEMORY_SCOPE_AGENT);
      __hip_atomic_store(pXY, (unsigned)(NT + LAG), __ATOMIC_RELEASE,
                         __HIP_MEMORY_SCOPE_AGENT);
    }
  } else if (role == 1) {
    // ========== P: layer-0 recurrence (hh only, 16 MFMA/wave) ==========
    half8 Ah[4][4];
#pragma unroll
    for (int q = 0; q < 4; ++q) {
      int row = (w + 8 * q) * 16 + n;
#pragma unroll
      for (int kt = 0; kt < 4; ++kt) {
        const float* wp = whh0 + (size_t)row * 128 + kt * 32 + lg * 4;
        Ah[q][kt] = cvt8(*(const float4*)wp, *(const float4*)(wp + 16));
      }
    }
    if (tid < 256) ((half8*)&hfr[1][0][0][0])[tid] = hz;  // h0[-1]=0
    f32x4 cst = {0.f, 0.f, 0.f, 0.f};
    unsigned Xp = wpoll(pX, 2u, 0u, l);
    f32x4 gA0 = *(const f32x4*)(gxG + ((0 + w) * 64 + l) * 4);
    f32x4 gA1 = *(const f32x4*)(gxG + ((8 + w) * 64 + l) * 4);
    f32x4 gA2 = *(const f32x4*)(gxG + ((16 + w) * 64 + l) * 4);
    f32x4 gA3 = *(const f32x4*)(gxG + ((24 + w) * 64 + l) * 4);
    const float* g1 = gxG + 8192;
    f32x4 gB0 = *(const f32x4*)(g1 + ((0 + w) * 64 + l) * 4);
    f32x4 gB1 = *(const f32x4*)(g1 + ((8 + w) * 64 + l) * 4);
    f32x4 gB2 = *(const f32x4*)(g1 + ((16 + w) * 64 + l) * 4);
    f32x4 gB3 = *(const f32x4*)(g1 + ((24 + w) * 64 + l) * 4);
    __syncthreads();

#define PSTEP(T, G0, G1, G2, G3)                                               \
  {                                                                            \
    const int rdk_ = ((T) + 1) & 1;                                            \
    half8 b0 = *(const half8*)&hfr[rdk_][0][l][0];                             \
    half8 b1 = *(const half8*)&hfr[rdk_][1][l][0];                             \
    half8 b2 = *(const half8*)&hfr[rdk_][2][l][0];                             \
    half8 b3 = *(const half8*)&hfr[rdk_][3][l][0];                             \
    f32x4 c0 = G0, c1 = G1, c2 = G2, c3 = G3;                                  \
    c0 = MFMA(Ah[0][0], b0, c0); c1 = MFMA(Ah[1][0], b0, c1);                  \
    c2 = MFMA(Ah[2][0], b0, c2); c3 = MFMA(Ah[3][0], b0, c3);                  \
    c0 = MFMA(Ah[0][1], b1, c0); c1 = MFMA(Ah[1][1], b1, c1);                  \
    c2 = MFMA(Ah[2][1], b1, c2); c3 = MFMA(Ah[3][1], b1, c3);                  \
    c0 = MFMA(Ah[0][2], b2, c0); c1 = MFMA(Ah[1][2], b2, c1);                  \
    c2 = MFMA(Ah[2][2], b2, c2); c3 = MFMA(Ah[3][2], b2, c3);                  \
    c0 = MFMA(Ah[0][3], b3, c0); c1 = MFMA(Ah[1][3], b3, c1);                  \
    c2 = MFMA(Ah[2][3], b3, c2); c3 = MFMA(Ah[3][3], b3, c3);                  \
    if ((T) + 2 < NT) { /* prefetch gx[T+2] (plain, flies over barrier) */     \
      Xp = wpoll(pX, (unsigned)((T) + 3), Xp, l);                              \
      const float* gp_ = gxG + (size_t)(((T) + 2) & (GS - 1)) * 8192;          \
      G0 = *(const f32x4*)(gp_ + ((0 + w) * 64 + l) * 4);                      \
      G1 = *(const f32x4*)(gp_ + ((8 + w) * 64 + l) * 4);                      \
      G2 = *(const f32x4*)(gp_ + ((16 + w) * 64 + l) * 4);                     \
      G3 = *(const f32x4*)(gp_ + ((24 + w) * 64 + l) * 4);                     \
    }                                                                          \
    half4 hh;                                                                  \
    _Pragma("unroll")                                                          \
    for (int r = 0; r < 4; ++r) {                                              \
      float iv = sigf(c0[r]), fv = sigf(c1[r]);                                \
      float gv = tanhf2(c2[r]), ov = sigf(c3[r]);                              \
      cst[r] = fv * cst[r] + iv * gv;                                          \
      hh[r] = (_Float16)(ov * tanhf2(cst[r]));                                 \
    }                                                                          \
    *(half4*)&hfr[(T) & 1][w >> 1][l][(w & 1) << 2] = hh;                      \
    *(u64*)(h0G + (size_t)((T) & (H0S - 1)) * 2048 + (w >> 1) * 512 + l * 8 +  \
            (w & 1) * 4) = __builtin_bit_cast(u64, hh);                        \
    LGKM_BARRIER();                                                            \
    if (((T) & 7) == 7) {                                                      \
      DRAIN_BARRIER();                                                         \
      if (tid == 0)                                                            \
        __hip_atomic_store(pP, (unsigned)((T) + 1), __ATOMIC_RELEASE,          \
                           __HIP_MEMORY_SCOPE_AGENT);                          \
    }                                                                          \
  }

    for (int s = 0; s < NT; s += 2) {
      PSTEP(s, gA0, gA1, gA2, gA3);
      PSTEP(s + 1, gB0, gB1, gB2, gB3);
    }
#undef PSTEP
  } else {
    // ======= Y: layer-1 recurrence (hh, 16 MFMA/wave) + FC + out =======
    half8 Ah[4][4], FCA[4];
    f32x4 fcbv = {0.f, 0.f, 0.f, 0.f};
#pragma unroll
    for (int q = 0; q < 4; ++q) {
      int row = (w + 8 * q) * 16 + n;
#pragma unroll
      for (int kt = 0; kt < 4; ++kt) {
        const float* wp = whh1 + (size_t)row * 128 + kt * 32 + lg * 4;
        Ah[q][kt] = cvt8(*(const float4*)wp, *(const float4*)(wp + 16));
      }
    }
    const bool fcon = (w < 4);
    if (fcon) {
      int frow = (w << 4) + n;
#pragma unroll
      for (int kt = 0; kt < 4; ++kt) {
        const float* wp = fcw + (size_t)frow * 128 + kt * 32 + lg * 4;
        FCA[kt] = cvt8(*(const float4*)wp, *(const float4*)(wp + 16));
      }
      fcbv = *(const f32x4*)(fcb + (w << 4) + lg * 4);
    }
    if (tid < 256) ((half8*)&hfr[1][0][0][0])[tid] = hz;  // h1[-1]=0
    float* outG = out + (size_t)((g << 4) + n) * NT * 64 + (w << 4) + lg * 4;
    f32x4 cst = {0.f, 0.f, 0.f, 0.f};
    unsigned XYp = wpoll(pXY, 2u, 0u, l);
    f32x4 gA0 = *(const f32x4*)(gyG + ((0 + w) * 64 + l) * 4);
    f32x4 gA1 = *(const f32x4*)(gyG + ((8 + w) * 64 + l) * 4);
    f32x4 gA2 = *(const f32x4*)(gyG + ((16 + w) * 64 + l) * 4);
    f32x4 gA3 = *(const f32x4*)(gyG + ((24 + w) * 64 + l) * 4);
    const float* g1 = gyG + 8192;
    f32x4 gB0 = *(const f32x4*)(g1 + ((0 + w) * 64 + l) * 4);
    f32x4 gB1 = *(const f32x4*)(g1 + ((8 + w) * 64 + l) * 4);
    f32x4 gB2 = *(const f32x4*)(g1 + ((16 + w) * 64 + l) * 4);
    f32x4 gB3 = *(const f32x4*)(g1 + ((24 + w) * 64 + l) * 4);
    __syncthreads();

#define YSTEP(T, G0, G1, G2, G3)                                               \
  {                                                                            \
    const int rdk_ = ((T) + 1) & 1;                                            \
    half8 b0 = *(const half8*)&hfr[rdk_][0][l][0];                             \
    half8 b1 = *(const half8*)&hfr[rdk_][1][l][0];                             \
    half8 b2 = *(const half8*)&hfr[rdk_][2][l][0];                             \
    half8 b3 = *(const half8*)&hfr[rdk_][3][l][0];                             \
    f32x4 c0 = G0, c1 = G1, c2 = G2, c3 = G3;                                  \
    c0 = MFMA(Ah[0][0], b0, c0); c1 = MFMA(Ah[1][0], b0, c1);                  \
    c2 = MFMA(Ah[2][0], b0, c2); c3 = MFMA(Ah[3][0], b0, c3);                  \
    c0 = MFMA(Ah[0][1], b1, c0); c1 = MFMA(Ah[1][1], b1, c1);                  \
    c2 = MFMA(Ah[2][1], b1, c2); c3 = MFMA(Ah[3][1], b1, c3);                  \
    c0 = MFMA(Ah[0][2], b2, c0); c1 = MFMA(Ah[1][2], b2, c1);                  \
    c2 = MFMA(Ah[2][2], b2, c2); c3 = MFMA(Ah[3][2], b2, c3);                  \
    c0 = MFMA(Ah[0][3], b3, c0); c1 = MFMA(Ah[1][3], b3, c1);                  \
    c2 = MFMA(Ah[2][3], b3, c2); c3 = MFMA(Ah[3][3], b3, c3);                  \
    if (fcon) { /* FC of h1[T-1] */                                            \
      f32x4 afc = fcbv;                                                        \
      afc = MFMA(FCA[0], b0, afc); afc = MFMA(FCA[1], b1, afc);                \
      afc = MFMA(FCA[2], b2, afc); afc = MFMA(FCA[3], b3, afc);                \
      if ((T) >= 1) *(f32x4*)(outG + (size_t)((T) - 1) * 64) = afc;            \
    }                                                                          \
    if ((T) + 2 < NT) { /* prefetch gy[T+2] */                                 \
      XYp = wpoll(pXY, (unsigned)((T) + 3), XYp, l);                           \
      const float* gp_ = gyG + (size_t)(((T) + 2) & (GS - 1)) * 8192;          \
      G0 = *(const f32x4*)(gp_ + ((0 + w) * 64 + l) * 4);                      \
      G1 = *(const f32x4*)(gp_ + ((8 + w) * 64 + l) * 4);                      \
      G2 = *(const f32x4*)(gp_ + ((16 + w) * 64 + l) * 4);                     \
      G3 = *(const f32x4*)(gp_ + ((24 + w) * 64 + l) * 4);                     \
    }                                                                          \
    half4 hh;                                                                  \
    _Pragma("unroll")                                                          \
    for (int r = 0; r < 4; ++r) {                                              \
      float iv = sigf(c0[r]), fv = sigf(c1[r]);                                \
      float gv = tanhf2(c2[r]), ov = sigf(c3[r]);                              \
      cst[r] = fv * cst[r] + iv * gv;                                          \
      hh[r] = (_Float16)(ov * tanhf2(cst[r]));                                 \
    }                                                                          \
    *(half4*)&hfr[(T) & 1][w >> 1][l][(w & 1) << 2] = hh;                      \
    LGKM_BARRIER();                                                            \
    if (((T) & 7) == 7 && tid == 0) /* consumption counter: relaxed ok */      \
      __hip_atomic_store(pY, (unsigned)((T) + 1), __ATOMIC_RELAXED,            \
                         __HIP_MEMORY_SCOPE_AGENT);                            \
  }

    for (int t = 0; t < NT; t += 2) {
      YSTEP(t, gA0, gA1, gA2, gA3);
      YSTEP(t + 1, gB0, gB1, gB2, gB3);
    }
#undef YSTEP
    {  // epilogue: FC of h1[NT-1] -> out[NT-1]
      const int rdk = (NT + 1) & 1;
      half8 b0 = *(const half8*)&hfr[rdk][0][l][0];
      half8 b1 = *(const half8*)&hfr[rdk][1][l][0];
      half8 b2 = *(const half8*)&hfr[rdk][2][l][0];
      half8 b3 = *(const half8*)&hfr[rdk][3][l][0];
      if (fcon) {
        f32x4 afc = fcbv;
        afc = MFMA(FCA[0], b0, afc); afc = MFMA(FCA[1], b1, afc);
        afc = MFMA(FCA[2], b2, afc); afc = MFMA(FCA[3], b3, afc);
        *(f32x4*)(outG + (size_t)(NT - 1) * 64) = afc;
      }
    }
  }
}

extern "C" void kernel_launch(void* const* d_in, const int* in_sizes, int n_in,
                              void* d_out, int out_size, void* d_ws, size_t ws_size,
                              hipStream_t stream) {
  const float* x     = (const float*)d_in[0];
  const float* w_ih0 = (const float*)d_in[1];
  const float* w_hh0 = (const float*)d_in[2];
  const float* w_ih1 = (const float*)d_in[3];
  const float* w_hh1 = (const float*)d_in[4];
  const float* b_ih  = (const float*)d_in[5];
  const float* b_hh  = (const float*)d_in[6];
  const float* fc_w  = (const float*)d_in[7];
  const float* fc_b  = (const float*)d_in[8];

  // ws: Xf 16MB | h0R 8MB | gxR 16MB | gyR 16MB | flags 4KB  (= 56MB+4KB)
  _Float16* Xf  = (_Float16*)d_ws;
  _Float16* h0R = (_Float16*)((char*)d_ws + (16u << 20));
  float* gxR    = (float*)((char*)d_ws + (24u << 20));
  float* gyR    = (float*)((char*)d_ws + (40u << 20));
  unsigned* flags = (unsigned*)((char*)d_ws + (56u << 20));

  (void)hipMemsetAsync(flags, 0, 4096, stream);
  prep_x<<<4096, 256, 0, stream>>>(x, Xf);
  lstm_main<<<24, 512, 0, stream>>>(w_ih0, w_hh0, w_ih1, w_hh1, b_ih, b_hh,
                                    fc_w, fc_b, Xf, h0R, gxR, gyR, flags,
                                    (float*)d_out);
}